// Round 1
// baseline (2086.766 us; speedup 1.0000x reference)
//
#include <hip/hip_runtime.h>
#include <hip/hip_bf16.h>

// TensorProductScatter: per-edge e3nn tensor product + segment_sum into out[dst].
// MUL=32. Layouts (all fp32):
//   x          : (N, 128)   x0 = x[:, 0:32], x1[u][i] = x[:, 32 + u*3 + i]
//   edge_attr  : (E, 4)     a0 = [:,0], a1 = [:,1:4]
//   edge_weight: (E, 160)   w_k[u] = [:, k*32 + u], k=0..4
//   out        : (N, 224)   [0:32)=out0, [32:128)=out1 (u*3+i), [128:224)=out2 (u*3+i)

#define MUL 32

__global__ __launch_bounds__(256) void tps_kernel(
    const float* __restrict__ x,
    const float* __restrict__ edge_attr,
    const float* __restrict__ edge_weight,
    const int* __restrict__ edge_dst,
    const int* __restrict__ edge_src,
    float* __restrict__ out,
    int E)
{
    const float INV_S2 = 0.7071067811865475f;
    const float INV_S3 = 0.5773502691896258f;

    int t = blockIdx.x * blockDim.x + threadIdx.x;
    int e = t >> 5;          // 32 threads per edge
    int u = t & 31;
    if (e >= E) return;

    int src = edge_src[e];
    int dst = edge_dst[e];

    const float* wb = edge_weight + (size_t)e * (5 * MUL);
    float w0 = wb[0 * MUL + u];
    float w1 = wb[1 * MUL + u];
    float w2 = wb[2 * MUL + u];
    float w3 = wb[3 * MUL + u];
    float w4 = wb[4 * MUL + u];

    const float* xb = x + (size_t)src * (4 * MUL);
    float xs0 = xb[u];
    float x1a = xb[MUL + u * 3 + 0];
    float x1b = xb[MUL + u * 3 + 1];
    float x1c = xb[MUL + u * 3 + 2];

    const float* ab = edge_attr + (size_t)e * 4;
    float a0  = ab[0];
    float a1x = ab[1];
    float a1y = ab[2];
    float a1z = ab[3];

    float dotv = x1a * a1x + x1b * a1y + x1c * a1z;

    float o0  = INV_S2 * (w0 * xs0 * a0 + w3 * (INV_S3 * dotv));

    float o1x = INV_S2 * (w1 * xs0 * a1x + w2 * x1a * a0);
    float o1y = INV_S2 * (w1 * xs0 * a1y + w2 * x1b * a0);
    float o1z = INV_S2 * (w1 * xs0 * a1z + w2 * x1c * a0);

    // cross(xs1, a1)
    float cx = x1b * a1z - x1c * a1y;
    float cy = x1c * a1x - x1a * a1z;
    float cz = x1a * a1y - x1b * a1x;
    float o2x = INV_S2 * w4 * cx;
    float o2y = INV_S2 * w4 * cy;
    float o2z = INV_S2 * w4 * cz;

    float* ob = out + (size_t)dst * (7 * MUL);
    atomicAdd(ob + u, o0);
    atomicAdd(ob + MUL + u * 3 + 0, o1x);
    atomicAdd(ob + MUL + u * 3 + 1, o1y);
    atomicAdd(ob + MUL + u * 3 + 2, o1z);
    atomicAdd(ob + 4 * MUL + u * 3 + 0, o2x);
    atomicAdd(ob + 4 * MUL + u * 3 + 1, o2y);
    atomicAdd(ob + 4 * MUL + u * 3 + 2, o2z);
}

extern "C" void kernel_launch(void* const* d_in, const int* in_sizes, int n_in,
                              void* d_out, int out_size, void* d_ws, size_t ws_size,
                              hipStream_t stream) {
    const float* x           = (const float*)d_in[0];
    const float* edge_attr   = (const float*)d_in[1];
    const float* edge_weight = (const float*)d_in[2];
    const int*   edge_dst    = (const int*)d_in[3];
    const int*   edge_src    = (const int*)d_in[4];
    float* out = (float*)d_out;

    int E = in_sizes[1] / 4;   // edge_attr is (E, 4)

    // d_out is poisoned 0xAA before every timed launch — zero it for the scatter.
    hipMemsetAsync(d_out, 0, (size_t)out_size * sizeof(float), stream);

    int threads_per_edge_total = E * 32;
    int block = 256;
    int grid = (threads_per_edge_total + block - 1) / block;
    tps_kernel<<<grid, block, 0, stream>>>(x, edge_attr, edge_weight,
                                           edge_dst, edge_src, out, E);
}

// Round 2
// 865.656 us; speedup vs baseline: 2.4106x; 2.4106x over previous
//
#include <hip/hip_runtime.h>
#include <hip/hip_bf16.h>

// TensorProductScatter, CSR-gather formulation.
// Layouts (fp32): x:(N,128) [x0=0:32, x1[u][i]=32+u*3+i], edge_attr:(E,4),
// edge_weight:(E,160) [w_k[u]=k*32+u], out:(N,224) [o0: u | o1: 32+u*3+i | o2: 128+u*3+i]
//
// ws layout (int32): deg[0,N) | cursor[N,2N) | offs[2N,3N) | eids[3N,3N+E)
// deg+cursor zeroed via one memsetAsync; offs/eids fully written each call.

#define MUL 32

__global__ __launch_bounds__(256) void hist_kernel(
    const int* __restrict__ dst, int* __restrict__ deg, int E)
{
    int e = blockIdx.x * blockDim.x + threadIdx.x;
    if (e < E) atomicAdd(&deg[dst[e]], 1);
}

// Single-block exclusive scan over N ints (N ~ 50k). 1024 threads = 16 waves.
__global__ __launch_bounds__(1024) void scan_kernel(
    const int* __restrict__ deg, int* __restrict__ offs, int N)
{
    __shared__ int wsum[16];
    __shared__ int carry_s;
    int tid = threadIdx.x, lane = tid & 63, wid = tid >> 6;
    if (tid == 0) carry_s = 0;
    __syncthreads();
    for (int base = 0; base < N; base += 1024) {
        int i = base + tid;
        int v = (i < N) ? deg[i] : 0;
        int iv = v;
        #pragma unroll
        for (int off = 1; off < 64; off <<= 1) {
            int tv = __shfl_up(iv, off, 64);
            if (lane >= off) iv += tv;
        }
        if (lane == 63) wsum[wid] = iv;
        __syncthreads();
        int woff = carry_s;
        for (int k = 0; k < wid; k++) woff += wsum[k];
        if (i < N) offs[i] = woff + iv - v;   // exclusive
        __syncthreads();
        if (tid == 0) {
            int tot = carry_s;
            for (int k = 0; k < 16; k++) tot += wsum[k];
            carry_s = tot;
        }
        __syncthreads();
    }
}

__global__ __launch_bounds__(256) void fill_kernel(
    const int* __restrict__ dst, const int* __restrict__ offs,
    int* __restrict__ cursor, int* __restrict__ eids, int E)
{
    int e = blockIdx.x * blockDim.x + threadIdx.x;
    if (e >= E) return;
    int d = dst[e];
    int pos = atomicAdd(&cursor[d], 1);
    eids[offs[d] + pos] = e;
}

// 64 lanes per node: lane&31 = u, lane>>5 = which alternate edge. No atomics.
__global__ __launch_bounds__(256) void tps_gather_kernel(
    const float* __restrict__ x,
    const float* __restrict__ edge_attr,
    const float* __restrict__ edge_weight,
    const int* __restrict__ edge_src,
    const int* __restrict__ offs,
    const int* __restrict__ deg,
    const int* __restrict__ eids,
    float* __restrict__ out, int N)
{
    const float INV_S2 = 0.7071067811865475f;
    const float INV_S3 = 0.5773502691896258f;

    int t = blockIdx.x * blockDim.x + threadIdx.x;
    int node = t >> 6;
    int lane = t & 63;
    int u = lane & 31;
    int half = lane >> 5;
    if (node >= N) return;

    int start = offs[node];
    int cnt = deg[node];

    float acc0 = 0.f, acc1x = 0.f, acc1y = 0.f, acc1z = 0.f;
    float acc2x = 0.f, acc2y = 0.f, acc2z = 0.f;

    for (int k = half; k < cnt; k += 2) {
        int e = eids[start + k];
        int s = edge_src[e];

        const float* wb = edge_weight + (size_t)e * 160;
        float w0 = wb[u], w1 = wb[32 + u], w2 = wb[64 + u];
        float w3 = wb[96 + u], w4 = wb[128 + u];

        const float* xb = x + (size_t)s * 128;
        float xs0 = xb[u];
        float x1a = xb[32 + u * 3], x1b = xb[33 + u * 3], x1c = xb[34 + u * 3];

        const float* ab = edge_attr + (size_t)e * 4;
        float a0 = ab[0], a1x = ab[1], a1y = ab[2], a1z = ab[3];

        float dotv = x1a * a1x + x1b * a1y + x1c * a1z;
        acc0  += w0 * xs0 * a0 + w3 * (INV_S3 * dotv);
        acc1x += w1 * xs0 * a1x + w2 * x1a * a0;
        acc1y += w1 * xs0 * a1y + w2 * x1b * a0;
        acc1z += w1 * xs0 * a1z + w2 * x1c * a0;
        acc2x += w4 * (x1b * a1z - x1c * a1y);
        acc2y += w4 * (x1c * a1x - x1a * a1z);
        acc2z += w4 * (x1a * a1y - x1b * a1x);
    }

    acc0  += __shfl_xor(acc0, 32, 64);
    acc1x += __shfl_xor(acc1x, 32, 64);
    acc1y += __shfl_xor(acc1y, 32, 64);
    acc1z += __shfl_xor(acc1z, 32, 64);
    acc2x += __shfl_xor(acc2x, 32, 64);
    acc2y += __shfl_xor(acc2y, 32, 64);
    acc2z += __shfl_xor(acc2z, 32, 64);

    if (half == 0) {
        float* ob = out + (size_t)node * 224;
        ob[u]              = INV_S2 * acc0;
        ob[32 + u * 3]     = INV_S2 * acc1x;
        ob[33 + u * 3]     = INV_S2 * acc1y;
        ob[34 + u * 3]     = INV_S2 * acc1z;
        ob[128 + u * 3]    = INV_S2 * acc2x;
        ob[129 + u * 3]    = INV_S2 * acc2y;
        ob[130 + u * 3]    = INV_S2 * acc2z;
    }
}

// Fallback (ws too small): original atomic version.
__global__ __launch_bounds__(256) void tps_atomic_kernel(
    const float* __restrict__ x, const float* __restrict__ edge_attr,
    const float* __restrict__ edge_weight, const int* __restrict__ edge_dst,
    const int* __restrict__ edge_src, float* __restrict__ out, int E)
{
    const float INV_S2 = 0.7071067811865475f;
    const float INV_S3 = 0.5773502691896258f;
    int t = blockIdx.x * blockDim.x + threadIdx.x;
    int e = t >> 5, u = t & 31;
    if (e >= E) return;
    int src = edge_src[e], dst = edge_dst[e];
    const float* wb = edge_weight + (size_t)e * 160;
    float w0 = wb[u], w1 = wb[32+u], w2 = wb[64+u], w3 = wb[96+u], w4 = wb[128+u];
    const float* xb = x + (size_t)src * 128;
    float xs0 = xb[u], x1a = xb[32+u*3], x1b = xb[33+u*3], x1c = xb[34+u*3];
    const float* ab = edge_attr + (size_t)e * 4;
    float a0 = ab[0], a1x = ab[1], a1y = ab[2], a1z = ab[3];
    float dotv = x1a*a1x + x1b*a1y + x1c*a1z;
    float* ob = out + (size_t)dst * 224;
    atomicAdd(ob + u, INV_S2 * (w0*xs0*a0 + w3*(INV_S3*dotv)));
    atomicAdd(ob + 32 + u*3, INV_S2 * (w1*xs0*a1x + w2*x1a*a0));
    atomicAdd(ob + 33 + u*3, INV_S2 * (w1*xs0*a1y + w2*x1b*a0));
    atomicAdd(ob + 34 + u*3, INV_S2 * (w1*xs0*a1z + w2*x1c*a0));
    atomicAdd(ob + 128 + u*3, INV_S2 * w4 * (x1b*a1z - x1c*a1y));
    atomicAdd(ob + 129 + u*3, INV_S2 * w4 * (x1c*a1x - x1a*a1z));
    atomicAdd(ob + 130 + u*3, INV_S2 * w4 * (x1a*a1y - x1b*a1x));
}

extern "C" void kernel_launch(void* const* d_in, const int* in_sizes, int n_in,
                              void* d_out, int out_size, void* d_ws, size_t ws_size,
                              hipStream_t stream) {
    const float* x           = (const float*)d_in[0];
    const float* edge_attr   = (const float*)d_in[1];
    const float* edge_weight = (const float*)d_in[2];
    const int*   edge_dst    = (const int*)d_in[3];
    const int*   edge_src    = (const int*)d_in[4];
    float* out = (float*)d_out;

    int E = in_sizes[1] / 4;     // edge_attr (E,4)
    int N = in_sizes[0] / 128;   // x (N,128)

    size_t need = ((size_t)3 * N + (size_t)E) * sizeof(int);
    if (ws_size < need) {
        hipMemsetAsync(d_out, 0, (size_t)out_size * sizeof(float), stream);
        int block = 256, grid = (E * 32 + block - 1) / block;
        tps_atomic_kernel<<<grid, block, 0, stream>>>(x, edge_attr, edge_weight,
                                                      edge_dst, edge_src, out, E);
        return;
    }

    int* deg    = (int*)d_ws;
    int* cursor = deg + N;
    int* offs   = cursor + N;
    int* eids   = offs + N;

    hipMemsetAsync(deg, 0, (size_t)2 * N * sizeof(int), stream);  // deg + cursor

    int block = 256;
    hist_kernel<<<(E + block - 1) / block, block, 0, stream>>>(edge_dst, deg, E);
    scan_kernel<<<1, 1024, 0, stream>>>(deg, offs, N);
    fill_kernel<<<(E + block - 1) / block, block, 0, stream>>>(edge_dst, offs, cursor, eids, E);

    int grid = ((N * 64) + block - 1) / block;   // 64 lanes per node
    tps_gather_kernel<<<grid, block, 0, stream>>>(x, edge_attr, edge_weight,
                                                  edge_src, offs, deg, eids, out, N);
}